// Round 8
// baseline (424.062 us; speedup 1.0000x reference)
//
#include <hip/hip_runtime.h>
#include <stdint.h>

#define NEGV    (-1000000000.0f)
#define CONF    0.05f
#define MAXSEL  550
#define CAP     32768
#define HEAD    1024
#define HW      16            // HEAD/64 mask words per row
#define MROWP   1025          // padded transposed-row stride (bank spread)
#define NBINS   4096
#define BINBASE 0xC07F0000u   // min key-hi for score in (0.05,1] minus margin
#define GCAP    3072          // max gathered head candidates
#define TROUNDS 3

typedef unsigned long long u64;
typedef unsigned int u32;

__device__ __forceinline__ float areaf(float4 b) {
    return __fmul_rn(fmaxf(__fsub_rn(b.z, b.x), 0.0f), fmaxf(__fsub_rn(b.w, b.y), 0.0f));
}

// Exact predicate for: __fdiv_rn(inter, max(uni,1e-8)) > 0.15f  (verified absmax 0 since R4).
// q_rn > 0.15f <=> exact quotient > M, M = midpoint(0.15f, next(0.15f)) = 0.15f + 2^-27.
// inter (24b) * M (25b) exact in double; comparison exact. No v_div sequence.
__device__ __forceinline__ bool iou_gt2(float4 a, float aA, float4 b, float aB) {
    float ltx = fmaxf(a.x, b.x), lty = fmaxf(a.y, b.y);
    float rbx = fminf(a.z, b.z), rby = fminf(a.w, b.w);
    float wx = fmaxf(__fsub_rn(rbx, ltx), 0.0f);
    float wy = fmaxf(__fsub_rn(rby, lty), 0.0f);
    float inter = __fmul_rn(wx, wy);
    float uni = fmaxf(__fsub_rn(__fadd_rn(aA, aB), inter), 1e-8f);
    const double M = (double)0.15f + 0x1p-27;
    return (double)inter > M * (double)uni;
}

__device__ __forceinline__ u32 binof(u32 keyhi) {
    u32 bin = (keyhi - BINBASE) >> 14;
    return bin > (NBINS - 1) ? (NBINS - 1) : bin;
}

// decode boxes; also zero hist[0], llen[0..1], S_arr, Sold
__global__ void k_decode(const float* __restrict__ pred, float4* __restrict__ boxes,
                         u32* __restrict__ hist0, u32* __restrict__ llen,
                         u32* __restrict__ S_arr, u32* __restrict__ Sold,
                         int BN, int NBC) {
    int t = blockIdx.x * 256 + threadIdx.x;
    if (t < NBC * NBINS) hist0[t] = 0;
    if (t < 2 * NBC) llen[t] = 0;
    if (t < NBC) { S_arr[t] = 0; Sold[t] = 0; }
    if (t >= BN) return;
    const float* p = pred + (size_t)t * 6;
    float cx = p[0], cy = p[1], w = p[2], h = p[3];
    float hw = __fmul_rn(w, 0.5f), hh = __fmul_rn(h, 0.5f);
    float4 b;
    b.x = __fsub_rn(cx, hw);
    b.y = __fsub_rn(cy, hh);
    b.z = __fadd_rn(cx, hw);
    b.w = __fadd_rn(cy, hh);
    boxes[t] = b;
}

// build candidate list (unordered) + histogram, per (b,c)
__global__ __launch_bounds__(256) void k_hist(const float* __restrict__ pred,
                                              u32* __restrict__ hist,
                                              u64* __restrict__ L0,
                                              u32* __restrict__ llen0,
                                              int Nn, int Cc, int TIL) {
    int bt = blockIdx.x;
    int tile = bt % TIL, bc = bt / TIL;
    int b = bc / Cc, c = bc % Cc;
    int n = tile * 256 + threadIdx.x;
    bool p = false; u32 hi = 0;
    if (n < Nn) {
        float lg = pred[((size_t)b * Nn + n) * 6 + 4 + c];
        float sc = __fdiv_rn(1.0f, __fadd_rn(1.0f, expf(-lg)));
        if (sc > CONF) {
            p = true;
            hi = ~__float_as_uint(sc);
            atomicAdd(&hist[bc * NBINS + binof(hi)], 1u);
        }
    }
    u64 bal = __ballot(p);
    __shared__ u32 wb[4]; __shared__ u32 base;
    int lane = threadIdx.x & 63, wv = threadIdx.x >> 6;
    if (lane == 0) wb[wv] = (u32)__popcll(bal);
    __syncthreads();
    if (threadIdx.x == 0) {
        u32 run = 0;
        for (int q = 0; q < 4; ++q) { u32 v = wb[q]; wb[q] = run; run += v; }
        base = run ? atomicAdd(&llen0[bc], run) : 0u;
    }
    __syncthreads();
    if (p) {
        u32 pos = base + wb[wv] + (u32)__popcll(bal & ((1ull << lane) - 1ull));
        if (pos < CAP)
            L0[(size_t)bc * CAP + pos] = ((u64)hi << 32) | (u32)n;
    }
}

// per-bc bin threshold t: smallest t with cum(t) >= min(HEAD, total); back off if cum(t) > GCAP.
// Also zeroes next round's hist + llen.
__global__ __launch_bounds__(1024) void k_thresh(const u32* __restrict__ hist,
                                                 int* __restrict__ tbin,
                                                 u32* __restrict__ histN,
                                                 u32* __restrict__ llenN,
                                                 int NBC) {
    int tid = threadIdx.x;
    for (int i = tid; i < NBC * NBINS; i += 1024) histN[i] = 0;
    if (tid < NBC) llenN[tid] = 0;
    int wv = tid >> 6, lane = tid & 63;
    if (wv < NBC) {
        const u32* h = hist + wv * NBINS;
        int base = lane * 64;
        u32 s = 0;
        for (int i = 0; i < 64; ++i) s += h[base + i];
        u32 p = s;
        for (int d = 1; d < 64; d <<= 1) { u32 o = __shfl_up(p, d); if (lane >= d) p += o; }
        u32 total = __shfl(p, 63);
        u32 K = total < HEAD ? total : HEAD;
        if (K > 0) {
            u64 bal = __ballot(p >= K);
            int tl = (int)__builtin_ctzll(bal);
            if (lane == tl) {
                u32 cum = p - s;
                for (int i = 0; i < 64; ++i) {
                    cum += h[base + i];
                    if (cum >= K) {
                        tbin[wv] = (cum <= GCAP) ? (base + i) : (base + i - 1);
                        break;
                    }
                }
            }
        } else if (lane == 0) tbin[wv] = -1;
    }
}

// gather bins<=t (<=GCAP keys), LDS bitonic sort, emit head (keys/boxes/areas), hl, Hmax
__global__ __launch_bounds__(1024) void k_headsort(const u64* __restrict__ list,
                                                   const u32* __restrict__ llen_cur,
                                                   const int* __restrict__ tbin,
                                                   const float4* __restrict__ boxes,
                                                   const u32* __restrict__ S_arr,
                                                   u64* __restrict__ headkey,
                                                   float4* __restrict__ headbox,
                                                   float* __restrict__ headarea,
                                                   u32* __restrict__ hl_arr,
                                                   u64* __restrict__ hmax_arr,
                                                   int Nn, int Cc) {
    int bc = blockIdx.x, b = bc / Cc;
    int tid = threadIdx.x;
    __shared__ u64 buf[4096];   // 32 KB
    __shared__ u32 gcnt;
    if (tid == 0) gcnt = 0;
    __syncthreads();
    if ((int)S_arr[bc] >= MAXSEL) { if (tid == 0) hl_arr[bc] = 0; return; }
    int t = tbin[bc];
    int len = (int)llen_cur[bc]; if (len > CAP) len = CAP;
    if (t >= 0) {
        const u64* src = list + (size_t)bc * CAP;
        for (int i = tid; i < len; i += 1024) {
            u64 key = src[i];
            if ((int)binof((u32)(key >> 32)) <= t) {
                u32 pos = atomicAdd(&gcnt, 1u);
                if (pos < GCAP) buf[pos] = key;
            }
        }
    }
    __syncthreads();
    int g = (int)gcnt; if (g > GCAP) g = GCAP;
    int SN = 1; while (SN < g) SN <<= 1;
    for (int i = g + tid; i < SN; i += 1024) buf[i] = ~0ull;
    __syncthreads();
    for (int k = 2; k <= SN; k <<= 1) {
        for (int j = k >> 1; j > 0; j >>= 1) {
            for (int idx = tid; idx < SN / 2; idx += 1024) {
                int i = ((idx & ~(j - 1)) << 1) | (idx & (j - 1));
                int q = i | j;
                bool up = ((i & k) == 0);
                u64 x = buf[i], y = buf[q];
                if ((x > y) == up) { buf[i] = y; buf[q] = x; }
            }
            __syncthreads();
        }
    }
    int hl = g < HEAD ? g : HEAD;
    if (tid == 0) { hl_arr[bc] = (u32)hl; hmax_arr[bc] = hl > 0 ? buf[hl - 1] : 0ull; }
    for (int i = tid; i < hl; i += 1024) {
        u64 key = buf[i];
        headkey[bc * HEAD + i] = key;
        float4 bx = boxes[(size_t)b * Nn + (u32)key];
        headbox[bc * HEAD + i] = bx;
        headarea[bc * HEAD + i] = areaf(bx);
    }
}

// transposed triangular suppression masks: masksT[bc][w][r] = word w of row r
__global__ __launch_bounds__(256) void k_premask(const float4* __restrict__ headbox,
                                                 const float* __restrict__ headarea,
                                                 const u32* __restrict__ hl_arr,
                                                 const u32* __restrict__ S_arr,
                                                 u64* __restrict__ masksT) {
    int blk = blockIdx.x, bc = blk >> 4, rb = blk & 15;
    int hl = (int)hl_arr[bc];
    if (hl <= 0 || (int)S_arr[bc] >= MAXSEL) return;
    __shared__ float4 chB[HEAD];
    __shared__ float  chA[HEAD];
    for (int i = threadIdx.x; i < hl; i += 256) {
        chB[i] = headbox[bc * HEAD + i];
        chA[i] = headarea[bc * HEAD + i];
    }
    __syncthreads();
    int r = (rb << 6) + (threadIdx.x & 63);
    int part = threadIdx.x >> 6;
    if (r >= hl) return;
    float4 a = chB[r]; float aA = chA[r];
    u64* mb = masksT + (size_t)bc * HW * MROWP;
    for (int w = part * 4; w < part * 4 + 4; ++w) {
        u64 bits = 0;
        int cb = w << 6;
        int j1 = hl - cb; if (j1 > 64) j1 = 64;
        int j0 = (cb > r) ? 0 : (r + 1 - cb);
        for (int j = j0; j < j1; ++j)
            if (iou_gt2(a, aA, chB[cb + j], chA[cb + j])) bits |= (1ull << j);
        mb[(size_t)w * MROWP + r] = bits;
    }
}

// batched-4 speculative bitmask chain: ~4 greedy selections per LDS round-trip
__global__ __launch_bounds__(1024) void k_chain(const u64* __restrict__ masksT,
                                                const u64* __restrict__ headkey,
                                                const float4* __restrict__ headbox,
                                                const float* __restrict__ headarea,
                                                const u32* __restrict__ hl_arr,
                                                u32* __restrict__ sel_n,
                                                float* __restrict__ sel_s,
                                                float4* __restrict__ selb_g,
                                                float* __restrict__ sela_g,
                                                u32* __restrict__ S_arr,
                                                u32* __restrict__ Sold) {
    int bc = blockIdx.x;
    int tid = threadIdx.x, lane = tid & 63;
    __shared__ u64 mrowT[HW * MROWP];   // 131.2 KB
    __shared__ u64 kky[HEAD];           // 8 KB
    __shared__ u32 selidx[MAXSEL];      // 2.2 KB
    __shared__ int s_S;
    int S0 = (int)S_arr[bc];
    if (tid == 0) Sold[bc] = (u32)S0;
    int hl = (int)hl_arr[bc];
    if (hl <= 0 || S0 >= MAXSEL) return;
    const u64* gm = masksT + (size_t)bc * HW * MROWP;
    for (int i = tid; i < HW * MROWP; i += 1024) mrowT[i] = gm[i];
    for (int i = tid; i < hl; i += 1024) kky[i] = headkey[bc * HEAD + i];
    __syncthreads();
    if (tid < 64) {
        u64 rem = ~0ull;
        if (lane < HW) {
            int lo = lane << 6;
            rem = (hl >= lo + 64) ? 0ull : (hl <= lo ? ~0ull : ~((1ull << (hl - lo)) - 1ull));
        }
        int S = S0;
        while (S < MAXSEL) {
            // extract up to 4 smallest alive indices (ascending)
            u64 w = (lane < HW) ? ~rem : 0ull;
            int idx0 = -1, idx1 = -1, idx2 = -1, idx3 = -1;
            int na = 0;
            #pragma unroll
            for (int rep = 0; rep < 4; ++rep) {
                u64 bal = __ballot(w != 0ull);
                if (!bal) break;
                int wl = (int)__builtin_ctzll(bal);
                u64 ww = __shfl(w, wl);
                int bit = (int)__builtin_ctzll(ww);
                int v = (wl << 6) + bit;
                if (rep == 0) idx0 = v; else if (rep == 1) idx1 = v;
                else if (rep == 2) idx2 = v; else idx3 = v;
                ++na;
                if (lane == wl) w &= w - 1ull;
            }
            if (na == 0) break;
            // 4 groups of 16 lanes each read one transposed row word
            int c = lane >> 4, wd = lane & 15;
            int myidx = (c == 0) ? idx0 : (c == 1) ? idx1 : (c == 2) ? idx2 : idx3;
            u64 roww = 0ull;
            if (c < na) roww = mrowT[(size_t)wd * MROWP + myidx];
            // K_c bit j: candidate idx_j suppressed by row c
            u32 kb = 0;
            if (c < na) {
                if (idx0 >= 0 && (idx0 >> 6) == wd && ((roww >> (idx0 & 63)) & 1ull)) kb |= 1u;
                if (idx1 >= 0 && (idx1 >> 6) == wd && ((roww >> (idx1 & 63)) & 1ull)) kb |= 2u;
                if (idx2 >= 0 && (idx2 >> 6) == wd && ((roww >> (idx2 & 63)) & 1ull)) kb |= 4u;
                if (idx3 >= 0 && (idx3 >> 6) == wd && ((roww >> (idx3 & 63)) & 1ull)) kb |= 8u;
            }
            kb |= __shfl_xor(kb, 1); kb |= __shfl_xor(kb, 2);
            kb |= __shfl_xor(kb, 4); kb |= __shfl_xor(kb, 8);
            u32 K0 = __shfl(kb, 0), K1 = __shfl(kb, 16), K2 = __shfl(kb, 32);
            // commit resolution (idx0 always; j killed only by committed earlier rows)
            u32 csel = 1;
            if (na > 1) { if (!((K0 >> 1) & 1)) csel |= 2; }
            if (na > 2) {
                u32 kill = ((K0 >> 2) & 1) | (((csel >> 1) & 1) & ((K1 >> 2) & 1));
                if (!kill) csel |= 4;
            }
            if (na > 3) {
                u32 kill = ((K0 >> 3) & 1) | (((csel >> 1) & 1) & ((K1 >> 3) & 1)) |
                           (((csel >> 2) & 1) & ((K2 >> 3) & 1));
                if (!kill) csel |= 8;
            }
            int room = MAXSEL - S;
            while (__builtin_popcount(csel) > room)
                csel &= ~(1u << (31 - __builtin_clz(csel)));
            if (lane == 0) {
                int s2 = S;
                if (csel & 1) selidx[s2++] = (u32)idx0;
                if (csel & 2) selidx[s2++] = (u32)idx1;
                if (csel & 4) selidx[s2++] = (u32)idx2;
                if (csel & 8) selidx[s2++] = (u32)idx3;
            }
            S += __builtin_popcount(csel);
            // rem update: shfls executed by ALL lanes (source lanes must be active)
            u64 r0 = __shfl(roww, (0 << 4) | (lane & 15));
            u64 r1 = __shfl(roww, (1 << 4) | (lane & 15));
            u64 r2 = __shfl(roww, (2 << 4) | (lane & 15));
            u64 r3 = __shfl(roww, (3 << 4) | (lane & 15));
            if (lane < HW) {
                if (csel & 1) rem |= r0;
                if (csel & 2) rem |= r1;
                if (csel & 4) rem |= r2;
                if (csel & 8) rem |= r3;
                if ((csel & 1) && (idx0 >> 6) == lane) rem |= 1ull << (idx0 & 63);
                if ((csel & 2) && (idx1 >> 6) == lane) rem |= 1ull << (idx1 & 63);
                if ((csel & 4) && (idx2 >> 6) == lane) rem |= 1ull << (idx2 & 63);
                if ((csel & 8) && (idx3 >> 6) == lane) rem |= 1ull << (idx3 & 63);
            }
        }
        if (lane == 0) { s_S = S; S_arr[bc] = (u32)S; }
    }
    __syncthreads();
    int S = s_S;
    for (int s = S0 + tid; s < S; s += 1024) {
        u32 i = selidx[s];
        u64 k64 = kky[i];
        sel_n[bc * MAXSEL + s] = (u32)k64;
        sel_s[bc * MAXSEL + s] = __uint_as_float(~(u32)(k64 >> 32));
        selb_g[bc * MAXSEL + s] = headbox[bc * HEAD + i];
        sela_g[bc * MAXSEL + s] = headarea[bc * HEAD + i];
    }
}

// rebuild survivor list: key > Hmax && !suppressed by new sels; skip when complete
__global__ __launch_bounds__(256) void k_mark(const u64* __restrict__ list,
                                              const u32* __restrict__ llen_cur,
                                              const float4* __restrict__ boxes,
                                              const float4* __restrict__ selb_g,
                                              const float* __restrict__ sela_g,
                                              const u32* __restrict__ S_arr,
                                              const u32* __restrict__ Sold,
                                              const u64* __restrict__ hmax_arr,
                                              const u32* __restrict__ hl_arr,
                                              u64* __restrict__ listN,
                                              u32* __restrict__ llenN,
                                              u32* __restrict__ histN,
                                              int Nn, int Cc) {
    int blk = blockIdx.x, bc = blk >> 6, seg = blk & 63;
    int tid = threadIdx.x, lane = tid & 63, wv = tid >> 6;
    int b = bc / Cc;
    int S0 = (int)Sold[bc], S1 = (int)S_arr[bc];
    if (S1 >= MAXSEL) return;                      // complete: next list stays empty
    int total = (int)llen_cur[bc]; if (total > CAP) total = CAP;
    if (total <= 0) return;
    int ns = S1 - S0;
    u64 hmax = ((int)hl_arr[bc] > 0) ? hmax_arr[bc] : 0ull;
    __shared__ float4 sb[MAXSEL];
    __shared__ float  sa[MAXSEL];
    for (int s = tid; s < ns; s += 256) {
        sb[s] = selb_g[bc * MAXSEL + S0 + s];
        sa[s] = sela_g[bc * MAXSEL + S0 + s];
    }
    __syncthreads();
    int chunk = (total + 63) / 64;
    int lo = seg * chunk, hi2 = lo + chunk; if (hi2 > total) hi2 = total;
    const u64* src = list + (size_t)bc * CAP;
    u64* dst = listN + (size_t)bc * CAP;
    __shared__ u32 wb[4]; __shared__ u32 base;
    for (int start = lo; start < hi2; start += 256) {
        int i = start + tid;
        bool alive = i < hi2;
        u64 key = 0;
        if (alive) {
            key = src[i];
            if (key <= hmax) alive = false;        // consumed in head
            if (alive) {
                float4 bx = boxes[(size_t)b * Nn + (u32)key];
                float aA = areaf(bx);
                for (int s = 0; s < ns; ++s)
                    if (iou_gt2(bx, aA, sb[s], sa[s])) { alive = false; break; }
            }
        }
        u64 bal = __ballot(alive);
        if (lane == 0) wb[wv] = (u32)__popcll(bal);
        __syncthreads();
        if (tid == 0) {
            u32 run = 0;
            for (int q = 0; q < 4; ++q) { u32 v = wb[q]; wb[q] = run; run += v; }
            base = run ? atomicAdd(&llenN[bc], run) : 0u;
        }
        __syncthreads();
        if (alive) {
            u32 pos = base + wb[wv] + (u32)__popcll(bal & ((1ull << lane) - 1ull));
            if (pos < CAP) dst[pos] = key;
            atomicAdd(&histN[bc * NBINS + binof((u32)(key >> 32))], 1u);
        }
        __syncthreads();
    }
}

// final: per-batch full sort of C*550 entries (== top_k) + output write
__global__ __launch_bounds__(1024) void k_final(const u32* __restrict__ selcnt,
                                                const u32* __restrict__ sel_n,
                                                const float* __restrict__ sel_s,
                                                const float4* __restrict__ boxes,
                                                float* __restrict__ out,
                                                int Nn, int Cc, int Bb) {
    int b = blockIdx.x, tid = threadIdx.x;
    const int TOT = MAXSEL * 2;   // 1100
    __shared__ u64 sk[2048];
    u32 c0 = selcnt[b * Cc + 0];
    u32 c1 = selcnt[b * Cc + 1];
    for (int t = tid; t < 2048; t += 1024) {
        u64 key;
        if (t < TOT) {
            int c = t / MAXSEL, k2 = t % MAXSEL;
            u32 cc = (c == 0) ? c0 : c1;
            float sc = (k2 < (int)cc) ? sel_s[(size_t)(b * Cc + c) * MAXSEL + k2] : NEGV;
            u32 u = __float_as_uint(sc);
            u32 ord = (u & 0x80000000u) ? ~u : (u | 0x80000000u);
            key = (((u64)(~ord)) << 32) | (u32)t;
        } else {
            key = ~0ull;
        }
        sk[t] = key;
    }
    __syncthreads();
    for (int k = 2; k <= 2048; k <<= 1) {
        for (int j = k >> 1; j > 0; j >>= 1) {
            int idx = tid;
            int i = ((idx & ~(j - 1)) << 1) | (idx & (j - 1));
            int p = i | j;
            bool up = ((i & k) == 0);
            u64 x = sk[i], y = sk[p];
            if ((x > y) == up) { sk[i] = y; sk[p] = x; }
            __syncthreads();
        }
    }
    int off_scores = Bb * TOT * 4;
    int off_classes = off_scores + Bb * TOT;
    int off_valid = off_classes + Bb * TOT;
    for (int r = tid; r < TOT; r += 1024) {
        u64 key = sk[r];
        u32 flat = (u32)(key & 0xffffffffull);
        u32 hi = (u32)(key >> 32);
        u32 ord = ~hi;
        float sc = (ord & 0x80000000u) ? __uint_as_float(ord & 0x7fffffffu)
                                       : __uint_as_float(~ord);
        bool valid = sc > -5.0e8f;
        int c = (int)(flat / MAXSEL), k2 = (int)(flat % MAXSEL);
        float4 bxv = make_float4(0.f, 0.f, 0.f, 0.f);
        float so = 0.f, co = 0.f;
        if (valid) {
            u32 n = sel_n[(size_t)(b * Cc + c) * MAXSEL + k2];
            bxv = boxes[(size_t)b * Nn + n];
            so = sc;
            co = (float)c;
        }
        ((float4*)out)[b * TOT + r] = bxv;
        out[off_scores + b * TOT + r] = so;
        out[off_classes + b * TOT + r] = co;
    }
    if (tid == 0) out[off_valid + b] = (float)(c0 + c1);
}

extern "C" void kernel_launch(void* const* d_in, const int* in_sizes, int n_in,
                              void* d_out, int out_size, void* d_ws, size_t ws_size,
                              hipStream_t stream) {
    const float* pred = (const float*)d_in[1];
    float* out = (float*)d_out;
    int Bb = out_size / 6601;            // 4
    int Nn = in_sizes[1] / (6 * Bb);     // 49104
    const int Cc = 2;
    if (Bb <= 0 || Nn <= 0) return;
    int NBC = Bb * Cc;                   // 8
    int TIL = (Nn + 255) / 256;          // 192

    char* ws = (char*)d_ws;
    size_t off = 0;
    auto alloc = [&](size_t bytes) { void* p = ws + off; off = (off + bytes + 255) & ~(size_t)255; return p; };
    float4* boxes   = (float4*)alloc((size_t)Bb * Nn * 16);
    u64* L0         = (u64*)alloc((size_t)NBC * CAP * 8);
    u64* L1         = (u64*)alloc((size_t)NBC * CAP * 8);
    u32* llen       = (u32*)alloc(2 * NBC * 4);
    u32* hist       = (u32*)alloc(2 * (size_t)NBC * NBINS * 4);
    int* tbin       = (int*)alloc(NBC * 4);
    u64* headkey    = (u64*)alloc((size_t)NBC * HEAD * 8);
    float4* headbox = (float4*)alloc((size_t)NBC * HEAD * 16);
    float* headarea = (float*)alloc((size_t)NBC * HEAD * 4);
    u32* hl_arr     = (u32*)alloc(NBC * 4);
    u64* hmax_arr   = (u64*)alloc(NBC * 8);
    u32* sel_n      = (u32*)alloc((size_t)NBC * MAXSEL * 4);
    float* sel_s    = (float*)alloc((size_t)NBC * MAXSEL * 4);
    float4* selb_g  = (float4*)alloc((size_t)NBC * MAXSEL * 16);
    float* sela_g   = (float*)alloc((size_t)NBC * MAXSEL * 4);
    u32* S_arr      = (u32*)alloc(NBC * 4);
    u32* Sold       = (u32*)alloc(NBC * 4);
    u64* masksT     = (u64*)alloc((size_t)NBC * HW * MROWP * 8);   // 1.05 MB
    if (off > ws_size) return;

    int BN = Bb * Nn;
    k_decode<<<(BN + 255) / 256, 256, 0, stream>>>(pred, boxes, hist, llen, S_arr, Sold, BN, NBC);
    k_hist<<<NBC * TIL, 256, 0, stream>>>(pred, hist, L0, llen, Nn, Cc, TIL);

    for (int r = 0; r < TROUNDS; ++r) {
        int cur = r & 1, nxt = (r + 1) & 1;
        u64* Lc = cur ? L1 : L0;
        u64* Ln = nxt ? L1 : L0;
        u32* lc = llen + cur * NBC;
        u32* ln = llen + nxt * NBC;
        u32* hc = hist + (size_t)cur * NBC * NBINS;
        u32* hn = hist + (size_t)nxt * NBC * NBINS;
        k_thresh<<<1, 1024, 0, stream>>>(hc, tbin, hn, ln, NBC);
        k_headsort<<<NBC, 1024, 0, stream>>>(Lc, lc, tbin, boxes, S_arr,
                                             headkey, headbox, headarea, hl_arr, hmax_arr, Nn, Cc);
        k_premask<<<NBC * 16, 256, 0, stream>>>(headbox, headarea, hl_arr, S_arr, masksT);
        k_chain<<<NBC, 1024, 0, stream>>>(masksT, headkey, headbox, headarea, hl_arr,
                                          sel_n, sel_s, selb_g, sela_g, S_arr, Sold);
        k_mark<<<NBC * 64, 256, 0, stream>>>(Lc, lc, boxes, selb_g, sela_g, S_arr, Sold,
                                             hmax_arr, hl_arr, Ln, ln, hn, Nn, Cc);
    }
    k_final<<<Bb, 1024, 0, stream>>>(S_arr, sel_n, sel_s, boxes, out, Nn, Cc, Bb);
}

// Round 10
// 377.936 us; speedup vs baseline: 1.1220x; 1.1220x over previous
//
#include <hip/hip_runtime.h>
#include <stdint.h>

#define NEGV    (-1000000000.0f)
#define CONF    0.05f
#define MAXSEL  550
#define CAP     32768
#define HEAD    1024
#define HW      (HEAD / 64)   // 16 u64 mask words per row
#define NBINS   4096
#define BINBASE 0xC07F0000u   // min key-hi for score in (0.05,1] minus margin
#define GCAP    3072          // max gathered head candidates
#define NSEG    64
#define TROUNDS 3

typedef unsigned long long u64;
typedef unsigned int u32;

__device__ __forceinline__ float areaf(float4 b) {
    return __fmul_rn(fmaxf(__fsub_rn(b.z, b.x), 0.0f), fmaxf(__fsub_rn(b.w, b.y), 0.0f));
}

// Exact predicate for: __fdiv_rn(inter, max(uni,1e-8)) > 0.15f  (verified absmax 0, R4-R8).
// q_rn > 0.15f <=> exact quotient > M, M = midpoint(0.15f, next(0.15f)) = 0.15f + 2^-27.
// inter (24b) * M (25b) exact in double; comparison exact. No v_div sequence.
__device__ __forceinline__ bool iou_gt2(float4 a, float aA, float4 b, float aB) {
    float ltx = fmaxf(a.x, b.x), lty = fmaxf(a.y, b.y);
    float rbx = fminf(a.z, b.z), rby = fminf(a.w, b.w);
    float wx = fmaxf(__fsub_rn(rbx, ltx), 0.0f);
    float wy = fmaxf(__fsub_rn(rby, lty), 0.0f);
    float inter = __fmul_rn(wx, wy);
    float uni = fmaxf(__fsub_rn(__fadd_rn(aA, aB), inter), 1e-8f);
    const double M = (double)0.15f + 0x1p-27;
    return (double)inter > M * (double)uni;
}

__device__ __forceinline__ u32 binof(u32 keyhi) {
    u32 bin = (keyhi - BINBASE) >> 14;
    return bin > (NBINS - 1) ? (NBINS - 1) : bin;
}

// decode boxes; also zero hist[0..1], llen[0..1], S_arr, Sold   [R8-proven]
__global__ void k_decode(const float* __restrict__ pred, float4* __restrict__ boxes,
                         u32* __restrict__ hist, u32* __restrict__ llen,
                         u32* __restrict__ S_arr, u32* __restrict__ Sold,
                         int BN, int NBC) {
    int t = blockIdx.x * 256 + threadIdx.x;
    if (t < 2 * NBC * NBINS) hist[t] = 0;
    if (t < 2 * NBC) llen[t] = 0;
    if (t < NBC) { S_arr[t] = 0; Sold[t] = 0; }
    if (t >= BN) return;
    const float* p = pred + (size_t)t * 6;
    float cx = p[0], cy = p[1], w = p[2], h = p[3];
    float hw = __fmul_rn(w, 0.5f), hh = __fmul_rn(h, 0.5f);
    float4 b;
    b.x = __fsub_rn(cx, hw);
    b.y = __fsub_rn(cy, hh);
    b.z = __fadd_rn(cx, hw);
    b.w = __fadd_rn(cy, hh);
    boxes[t] = b;
}

// candidate list (unordered) + histogram, per (b,c)   [R8-proven]
__global__ __launch_bounds__(256) void k_hist(const float* __restrict__ pred,
                                              u32* __restrict__ hist,
                                              u64* __restrict__ L0,
                                              u32* __restrict__ llen0,
                                              int Nn, int Cc, int TIL) {
    int bt = blockIdx.x;
    int tile = bt % TIL, bc = bt / TIL;
    int b = bc / Cc, c = bc % Cc;
    int n = tile * 256 + threadIdx.x;
    bool p = false; u32 hi = 0;
    if (n < Nn) {
        float lg = pred[((size_t)b * Nn + n) * 6 + 4 + c];
        float sc = __fdiv_rn(1.0f, __fadd_rn(1.0f, expf(-lg)));
        if (sc > CONF) {
            p = true;
            hi = ~__float_as_uint(sc);
            atomicAdd(&hist[bc * NBINS + binof(hi)], 1u);
        }
    }
    u64 bal = __ballot(p);
    __shared__ u32 wb[4]; __shared__ u32 base;
    int lane = threadIdx.x & 63, wv = threadIdx.x >> 6;
    if (lane == 0) wb[wv] = (u32)__popcll(bal);
    __syncthreads();
    if (threadIdx.x == 0) {
        u32 run = 0;
        for (int q = 0; q < 4; ++q) { u32 v = wb[q]; wb[q] = run; run += v; }
        base = run ? atomicAdd(&llen0[bc], run) : 0u;
    }
    __syncthreads();
    if (p) {
        u32 pos = base + wb[wv] + (u32)__popcll(bal & ((1ull << lane) - 1ull));
        if (pos < CAP)
            L0[(size_t)bc * CAP + pos] = ((u64)hi << 32) | (u32)n;
    }
}

// per-bc bin threshold t: smallest t with cum(t) >= min(HEAD, total); back off if cum > GCAP.
// Also zeroes next round's hist + llen.   [R8-proven]
__global__ __launch_bounds__(1024) void k_thresh(const u32* __restrict__ hist,
                                                 int* __restrict__ tbin,
                                                 u32* __restrict__ histN,
                                                 u32* __restrict__ llenN,
                                                 int NBC) {
    int tid = threadIdx.x;
    for (int i = tid; i < NBC * NBINS; i += 1024) histN[i] = 0;
    if (tid < NBC) llenN[tid] = 0;
    int wv = tid >> 6, lane = tid & 63;
    if (wv < NBC) {
        const u32* h = hist + wv * NBINS;
        int base = lane * 64;
        u32 s = 0;
        for (int i = 0; i < 64; ++i) s += h[base + i];
        u32 p = s;
        for (int d = 1; d < 64; d <<= 1) { u32 o = __shfl_up(p, d); if (lane >= d) p += o; }
        u32 total = __shfl(p, 63);
        u32 K = total < HEAD ? total : HEAD;
        if (K > 0) {
            u64 bal = __ballot(p >= K);
            int tl = (int)__builtin_ctzll(bal);
            if (lane == tl) {
                u32 cum = p - s;
                for (int i = 0; i < 64; ++i) {
                    cum += h[base + i];
                    if (cum >= K) {
                        tbin[wv] = (cum <= GCAP) ? (base + i) : (base + i - 1);
                        break;
                    }
                }
            }
        } else if (lane == 0) tbin[wv] = -1;
    }
}

// gather bins<=t (<=GCAP keys), LDS bitonic sort, emit head (keys/boxes/areas), hl, Hmax
// [R8-proven]
__global__ __launch_bounds__(1024) void k_headsort(const u64* __restrict__ list,
                                                   const u32* __restrict__ llen_cur,
                                                   const int* __restrict__ tbin,
                                                   const float4* __restrict__ boxes,
                                                   const u32* __restrict__ S_arr,
                                                   u64* __restrict__ headkey,
                                                   float4* __restrict__ headbox,
                                                   float* __restrict__ headarea,
                                                   u32* __restrict__ hl_arr,
                                                   u64* __restrict__ hmax_arr,
                                                   int Nn, int Cc) {
    int bc = blockIdx.x, b = bc / Cc;
    int tid = threadIdx.x;
    __shared__ u64 buf[4096];   // 32 KB
    __shared__ u32 gcnt;
    if (tid == 0) gcnt = 0;
    __syncthreads();
    if ((int)S_arr[bc] >= MAXSEL) { if (tid == 0) hl_arr[bc] = 0; return; }
    int t = tbin[bc];
    int len = (int)llen_cur[bc]; if (len > CAP) len = CAP;
    if (t >= 0) {
        const u64* src = list + (size_t)bc * CAP;
        for (int i = tid; i < len; i += 1024) {
            u64 key = src[i];
            if ((int)binof((u32)(key >> 32)) <= t) {
                u32 pos = atomicAdd(&gcnt, 1u);
                if (pos < GCAP) buf[pos] = key;
            }
        }
    }
    __syncthreads();
    int g = (int)gcnt; if (g > GCAP) g = GCAP;
    int SN = 1; while (SN < g) SN <<= 1;
    for (int i = g + tid; i < SN; i += 1024) buf[i] = ~0ull;
    __syncthreads();
    for (int k = 2; k <= SN; k <<= 1) {
        for (int j = k >> 1; j > 0; j >>= 1) {
            for (int idx = tid; idx < SN / 2; idx += 1024) {
                int i = ((idx & ~(j - 1)) << 1) | (idx & (j - 1));
                int q = i | j;
                bool up = ((i & k) == 0);
                u64 x = buf[i], y = buf[q];
                if ((x > y) == up) { buf[i] = y; buf[q] = x; }
            }
            __syncthreads();
        }
    }
    int hl = g < HEAD ? g : HEAD;
    if (tid == 0) { hl_arr[bc] = (u32)hl; hmax_arr[bc] = hl > 0 ? buf[hl - 1] : 0ull; }
    for (int i = tid; i < hl; i += 1024) {
        u64 key = buf[i];
        headkey[bc * HEAD + i] = key;
        float4 bx = boxes[(size_t)b * Nn + (u32)key];
        headbox[bc * HEAD + i] = bx;
        headarea[bc * HEAD + i] = areaf(bx);
    }
}

// triangular suppression masks, row-major u64: masks[bc][r][w]   [R7-proven layout/body]
__global__ __launch_bounds__(256) void k_premask(const float4* __restrict__ headbox,
                                                 const float* __restrict__ headarea,
                                                 const u32* __restrict__ hl_arr,
                                                 u64* __restrict__ masks) {
    int blk = blockIdx.x, bc = blk >> 4, rb = blk & 15;
    int hl = (int)hl_arr[bc];
    if (hl <= 0) return;
    __shared__ float4 chB[HEAD];
    __shared__ float  chA[HEAD];
    for (int i = threadIdx.x; i < hl; i += 256) {
        chB[i] = headbox[bc * HEAD + i];
        chA[i] = headarea[bc * HEAD + i];
    }
    __syncthreads();
    int r = (rb << 6) + (threadIdx.x & 63);
    int part = threadIdx.x >> 6;               // 0..3
    if (r >= hl) return;
    float4 a = chB[r]; float aA = chA[r];
    u64* row = masks + ((size_t)bc * HEAD + r) * HW;
    for (int w = part * 4; w < part * 4 + 4; ++w) {
        u64 bits = 0;
        int cb = w << 6;
        int j1 = hl - cb; if (j1 > 64) j1 = 64;
        int j0 = (cb > r) ? 0 : (r + 1 - cb);
        for (int j = j0; j < j1; ++j)
            if (iou_gt2(a, aA, chB[cb + j], chA[cb + j])) bits |= (1ull << j);
        row[w] = bits;
    }
}

// Pure-bitmask greedy chain over the head (wave 0). Removed mask: lanes 0..15 hold one
// u64 each. Per selection: ballot -> ctz -> shfl -> one 16-lane LDS row read -> OR.
// [R7-proven walk; R8-proven tail incl. selb_g/sela_g gather]
__global__ __launch_bounds__(1024) void k_chain(const u64* __restrict__ headkey,
                                                const u32* __restrict__ hl_arr,
                                                const u64* __restrict__ masks,
                                                const float4* __restrict__ headbox,
                                                const float* __restrict__ headarea,
                                                u32* __restrict__ sel_n,
                                                float* __restrict__ sel_s,
                                                float4* __restrict__ selb_g,
                                                float* __restrict__ sela_g,
                                                u32* __restrict__ S_arr,
                                                u32* __restrict__ Sold) {
    int bc = blockIdx.x;
    int tid = threadIdx.x, lane = tid & 63;
    __shared__ u64 mrow[HEAD * HW];   // 128 KB
    __shared__ u64 kky[HEAD];         // 8 KB
    __shared__ u32 selidx[MAXSEL];
    __shared__ int s_S;
    int S0 = (int)S_arr[bc];
    if (tid == 0) Sold[bc] = (u32)S0;
    int hl = (int)hl_arr[bc];
    if (hl <= 0 || S0 >= MAXSEL) return;   // uniform
    const u64* gm = masks + (size_t)bc * HEAD * HW;
    for (int i = tid; i < hl * HW; i += 1024) mrow[i] = gm[i];
    for (int i = tid; i < hl; i += 1024) kky[i] = headkey[bc * HEAD + i];
    __syncthreads();
    if (tid < 64) {                   // wave 0 walks
        u64 rem = ~0ull;
        if (lane < HW) {
            int lo = lane << 6;
            rem = (hl >= lo + 64) ? 0ull : (hl <= lo ? ~0ull : ~((1ull << (hl - lo)) - 1ull));
        }
        int S = S0;
        while (S < MAXSEL) {
            bool av = (lane < HW) && (rem != ~0ull);
            u64 bal = __ballot(av);
            if (!bal) break;
            int w0 = (int)__builtin_ctzll(bal);
            u64 nz = __shfl((u64)(~rem), w0);
            int kz = (int)__builtin_ctzll(nz);
            int i = (w0 << 6) + kz;
            if (lane == 0) selidx[S] = (u32)i;
            if (lane < HW) rem |= mrow[i * HW + lane];
            if (lane == w0) rem |= (1ull << kz);
            ++S;
        }
        if (lane == 0) { s_S = S; S_arr[bc] = (u32)S; }
    }
    __syncthreads();
    int S = s_S;
    for (int s = S0 + tid; s < S; s += 1024) {
        u32 i = selidx[s];
        u64 k64 = kky[i];
        sel_n[bc * MAXSEL + s] = (u32)k64;
        sel_s[bc * MAXSEL + s] = __uint_as_float(~(u32)(k64 >> 32));
        selb_g[bc * MAXSEL + s] = headbox[bc * HEAD + i];
        sela_g[bc * MAXSEL + s] = headarea[bc * HEAD + i];
    }
}

// survivor rebuild for next round; skips (kills list) when S >= MAXSEL
__global__ __launch_bounds__(256) void k_mark(const float4* __restrict__ boxes,
                                              const u64* __restrict__ Lc,
                                              const u32* __restrict__ llen_c,
                                              const float4* __restrict__ selb_g,
                                              const float* __restrict__ sela_g,
                                              const u32* __restrict__ S_arr,
                                              const u32* __restrict__ Sold,
                                              const u64* __restrict__ hmax_arr,
                                              const u32* __restrict__ hl_arr,
                                              u64* __restrict__ Ln,
                                              u32* __restrict__ llen_n,
                                              u32* __restrict__ hist_n,
                                              int Nn, int Cc) {
    int blk = blockIdx.x, bc = blk / NSEG, seg = blk % NSEG;
    int tid = threadIdx.x, lane = tid & 63, wv = tid >> 6;
    int b = bc / Cc;
    int S0 = (int)Sold[bc], S1 = (int)S_arr[bc];
    if (S1 >= MAXSEL) return;                       // complete: next list stays empty
    int len = (int)llen_c[bc]; if (len > CAP) len = CAP;
    if (len <= 0) return;
    int ns = S1 - S0;
    u64 hmax = ((int)hl_arr[bc] > 0) ? hmax_arr[bc] : 0ull;
    __shared__ float4 sb[MAXSEL];
    __shared__ float  sa[MAXSEL];
    for (int s = tid; s < ns; s += 256) {
        sb[s] = selb_g[bc * MAXSEL + S0 + s];
        sa[s] = sela_g[bc * MAXSEL + S0 + s];
    }
    __syncthreads();
    __shared__ u32 wb[4]; __shared__ u32 base;
    int chunk = (len + NSEG - 1) / NSEG;
    int lo = seg * chunk, hi2 = lo + chunk; if (hi2 > len) hi2 = len;
    const u64* src = Lc + (size_t)bc * CAP;
    u64* dst = Ln + (size_t)bc * CAP;
    for (int st = lo; st < hi2; st += 256) {
        int i = st + tid;
        bool alive = i < hi2; u64 key = 0;
        if (alive) {
            key = src[i];
            if (key <= hmax) alive = false;         // consumed in head
            else {
                float4 bx = boxes[(size_t)b * Nn + (u32)key];
                float aA = areaf(bx);
                for (int s = 0; s < ns; ++s)
                    if (iou_gt2(bx, aA, sb[s], sa[s])) { alive = false; break; }
            }
        }
        u64 bal = __ballot(alive);
        if (lane == 0) wb[wv] = (u32)__popcll(bal);
        __syncthreads();
        if (tid == 0) {
            u32 run = 0;
            for (int q = 0; q < 4; ++q) { u32 v = wb[q]; wb[q] = run; run += v; }
            base = run ? atomicAdd(&llen_n[bc], run) : 0u;
        }
        __syncthreads();
        if (alive) {
            u32 pos = base + wb[wv] + (u32)__popcll(bal & ((1ull << lane) - 1ull));
            if (pos < CAP) dst[pos] = key;
            atomicAdd(&hist_n[bc * NBINS + binof((u32)(key >> 32))], 1u);
        }
        __syncthreads();                            // wb reused next iteration
    }
}

// final: per-batch full sort of C*550 entries (== top_k) + output write   [R7/R8-proven]
__global__ __launch_bounds__(1024) void k_final(const u32* __restrict__ selcnt,
                                                const u32* __restrict__ sel_n,
                                                const float* __restrict__ sel_s,
                                                const float4* __restrict__ boxes,
                                                float* __restrict__ out,
                                                int Nn, int Cc, int Bb) {
    int b = blockIdx.x, tid = threadIdx.x;
    const int TOT = MAXSEL * 2;   // 1100
    __shared__ u64 sk[2048];
    u32 c0 = selcnt[b * Cc + 0];
    u32 c1 = selcnt[b * Cc + 1];
    for (int t = tid; t < 2048; t += 1024) {
        u64 key;
        if (t < TOT) {
            int c = t / MAXSEL, k2 = t % MAXSEL;
            u32 cc = (c == 0) ? c0 : c1;
            float sc = (k2 < (int)cc) ? sel_s[(size_t)(b * Cc + c) * MAXSEL + k2] : NEGV;
            u32 u = __float_as_uint(sc);
            u32 ord = (u & 0x80000000u) ? ~u : (u | 0x80000000u);
            key = (((u64)(~ord)) << 32) | (u32)t;
        } else {
            key = ~0ull;
        }
        sk[t] = key;
    }
    __syncthreads();
    for (int k = 2; k <= 2048; k <<= 1) {
        for (int j = k >> 1; j > 0; j >>= 1) {
            int idx = tid;
            int i = ((idx & ~(j - 1)) << 1) | (idx & (j - 1));
            int p = i | j;
            bool up = ((i & k) == 0);
            u64 x = sk[i], y = sk[p];
            if ((x > y) == up) { sk[i] = y; sk[p] = x; }
            __syncthreads();
        }
    }
    int off_scores = Bb * TOT * 4;
    int off_classes = off_scores + Bb * TOT;
    int off_valid = off_classes + Bb * TOT;
    for (int r = tid; r < TOT; r += 1024) {
        u64 key = sk[r];
        u32 flat = (u32)(key & 0xffffffffull);
        u32 hi = (u32)(key >> 32);
        u32 ord = ~hi;
        float sc = (ord & 0x80000000u) ? __uint_as_float(ord & 0x7fffffffu)
                                       : __uint_as_float(~ord);
        bool valid = sc > -5.0e8f;
        int c = (int)(flat / MAXSEL), k2 = (int)(flat % MAXSEL);
        float4 bxv = make_float4(0.f, 0.f, 0.f, 0.f);
        float so = 0.f, co = 0.f;
        if (valid) {
            u32 n = sel_n[(size_t)(b * Cc + c) * MAXSEL + k2];
            bxv = boxes[(size_t)b * Nn + n];
            so = sc;
            co = (float)c;
        }
        ((float4*)out)[b * TOT + r] = bxv;
        out[off_scores + b * TOT + r] = so;
        out[off_classes + b * TOT + r] = co;
    }
    if (tid == 0) out[off_valid + b] = (float)(c0 + c1);
}

extern "C" void kernel_launch(void* const* d_in, const int* in_sizes, int n_in,
                              void* d_out, int out_size, void* d_ws, size_t ws_size,
                              hipStream_t stream) {
    const float* pred = (const float*)d_in[1];
    float* out = (float*)d_out;
    int Bb = out_size / 6601;            // 4
    int Nn = in_sizes[1] / (6 * Bb);     // 49104
    const int Cc = 2;
    if (Bb <= 0 || Nn <= 0) return;
    int NBC = Bb * Cc;                   // 8
    int TIL = (Nn + 255) / 256;          // 192

    char* ws = (char*)d_ws;
    size_t off = 0;
    auto alloc = [&](size_t bytes) { void* p = ws + off; off = (off + bytes + 255) & ~(size_t)255; return p; };
    float4* boxes   = (float4*)alloc((size_t)Bb * Nn * 16);
    u64* L0         = (u64*)alloc((size_t)NBC * CAP * 8);
    u64* L1         = (u64*)alloc((size_t)NBC * CAP * 8);
    u32* hist       = (u32*)alloc(2 * (size_t)NBC * NBINS * 4);
    u32* llen       = (u32*)alloc(2 * NBC * 4);
    int* tbin       = (int*)alloc(NBC * 4);
    u64* headkey    = (u64*)alloc((size_t)NBC * HEAD * 8);
    float4* headbox = (float4*)alloc((size_t)NBC * HEAD * 16);
    float* headarea = (float*)alloc((size_t)NBC * HEAD * 4);
    u32* hl_arr     = (u32*)alloc(NBC * 4);
    u64* hmax_arr   = (u64*)alloc(NBC * 8);
    u32* sel_n      = (u32*)alloc((size_t)NBC * MAXSEL * 4);
    float* sel_s    = (float*)alloc((size_t)NBC * MAXSEL * 4);
    float4* selb_g  = (float4*)alloc((size_t)NBC * MAXSEL * 16);
    float* sela_g   = (float*)alloc((size_t)NBC * MAXSEL * 4);
    u32* S_arr      = (u32*)alloc(NBC * 4);
    u32* Sold       = (u32*)alloc(NBC * 4);
    u64* masks      = (u64*)alloc((size_t)NBC * HEAD * HW * 8);   // 1 MB
    if (off > ws_size) return;

    int BN = Bb * Nn;
    k_decode<<<(BN + 255) / 256, 256, 0, stream>>>(pred, boxes, hist, llen, S_arr, Sold, BN, NBC);
    k_hist<<<NBC * TIL, 256, 0, stream>>>(pred, hist, L0, llen, Nn, Cc, TIL);

    for (int r = 0; r < TROUNDS; ++r) {
        int cur = r & 1, nxt = (r + 1) & 1;
        u64* Lc = cur ? L1 : L0;
        u64* Ln = nxt ? L1 : L0;
        u32* lc = llen + cur * NBC;
        u32* ln = llen + nxt * NBC;
        u32* hc = hist + (size_t)cur * NBC * NBINS;
        u32* hn = hist + (size_t)nxt * NBC * NBINS;
        k_thresh<<<1, 1024, 0, stream>>>(hc, tbin, hn, ln, NBC);
        k_headsort<<<NBC, 1024, 0, stream>>>(Lc, lc, tbin, boxes, S_arr,
                                             headkey, headbox, headarea, hl_arr, hmax_arr, Nn, Cc);
        k_premask<<<NBC * 16, 256, 0, stream>>>(headbox, headarea, hl_arr, masks);
        k_chain<<<NBC, 1024, 0, stream>>>(headkey, hl_arr, masks, headbox, headarea,
                                          sel_n, sel_s, selb_g, sela_g, S_arr, Sold);
        if (r + 1 < TROUNDS)
            k_mark<<<NBC * NSEG, 256, 0, stream>>>(boxes, Lc, lc, selb_g, sela_g, S_arr, Sold,
                                                   hmax_arr, hl_arr, Ln, ln, hn, Nn, Cc);
    }
    k_final<<<Bb, 1024, 0, stream>>>(S_arr, sel_n, sel_s, boxes, out, Nn, Cc, Bb);
}

// Round 13
// 359.188 us; speedup vs baseline: 1.1806x; 1.0522x over previous
//
#include <hip/hip_runtime.h>
#include <stdint.h>

#define NEGV    (-1000000000.0f)
#define CONF    0.05f
#define MAXSEL  550
#define CAP     32768
#define HEAD    1024
#define HW      (HEAD / 64)   // 16 u64 mask words per row
#define NBINS   4096
#define BINBASE 0xC07F0000u   // min key-hi for score in (0.05,1] minus margin
#define GCAP    3072          // max gathered head candidates
#define NSEG    64
#define TROUNDS 3

typedef unsigned long long u64;
typedef unsigned int u32;

__device__ __forceinline__ float areaf(float4 b) {
    return __fmul_rn(fmaxf(__fsub_rn(b.z, b.x), 0.0f), fmaxf(__fsub_rn(b.w, b.y), 0.0f));
}

// Exact predicate for: __fdiv_rn(inter, max(uni,1e-8)) > 0.15f  (verified absmax 0, R4-R10).
// q_rn > 0.15f <=> exact quotient > M, M = midpoint(0.15f, next(0.15f)) = 0.15f + 2^-27.
// inter (24b) * M (25b) exact in double; comparison exact. No v_div sequence.
__device__ __forceinline__ bool iou_gt2(float4 a, float aA, float4 b, float aB) {
    float ltx = fmaxf(a.x, b.x), lty = fmaxf(a.y, b.y);
    float rbx = fminf(a.z, b.z), rby = fminf(a.w, b.w);
    float wx = fmaxf(__fsub_rn(rbx, ltx), 0.0f);
    float wy = fmaxf(__fsub_rn(rby, lty), 0.0f);
    float inter = __fmul_rn(wx, wy);
    float uni = fmaxf(__fsub_rn(__fadd_rn(aA, aB), inter), 1e-8f);
    const double M = (double)0.15f + 0x1p-27;
    return (double)inter > M * (double)uni;
}

__device__ __forceinline__ u32 binof(u32 keyhi) {
    u32 bin = (keyhi - BINBASE) >> 14;
    return bin > (NBINS - 1) ? (NBINS - 1) : bin;
}

// decode boxes; also zero hist[0..1], llen[0..1], S_arr, Sold   [R10-proven]
__global__ void k_decode(const float* __restrict__ pred, float4* __restrict__ boxes,
                         u32* __restrict__ hist, u32* __restrict__ llen,
                         u32* __restrict__ S_arr, u32* __restrict__ Sold,
                         int BN, int NBC) {
    int t = blockIdx.x * 256 + threadIdx.x;
    if (t < 2 * NBC * NBINS) hist[t] = 0;
    if (t < 2 * NBC) llen[t] = 0;
    if (t < NBC) { S_arr[t] = 0; Sold[t] = 0; }
    if (t >= BN) return;
    const float* p = pred + (size_t)t * 6;
    float cx = p[0], cy = p[1], w = p[2], h = p[3];
    float hw = __fmul_rn(w, 0.5f), hh = __fmul_rn(h, 0.5f);
    float4 b;
    b.x = __fsub_rn(cx, hw);
    b.y = __fsub_rn(cy, hh);
    b.z = __fadd_rn(cx, hw);
    b.w = __fadd_rn(cy, hh);
    boxes[t] = b;
}

// candidate list (unordered) + histogram, per (b,c)   [R10-proven]
__global__ __launch_bounds__(256) void k_hist(const float* __restrict__ pred,
                                              u32* __restrict__ hist,
                                              u64* __restrict__ L0,
                                              u32* __restrict__ llen0,
                                              int Nn, int Cc, int TIL) {
    int bt = blockIdx.x;
    int tile = bt % TIL, bc = bt / TIL;
    int b = bc / Cc, c = bc % Cc;
    int n = tile * 256 + threadIdx.x;
    bool p = false; u32 hi = 0;
    if (n < Nn) {
        float lg = pred[((size_t)b * Nn + n) * 6 + 4 + c];
        float sc = __fdiv_rn(1.0f, __fadd_rn(1.0f, expf(-lg)));
        if (sc > CONF) {
            p = true;
            hi = ~__float_as_uint(sc);
            atomicAdd(&hist[bc * NBINS + binof(hi)], 1u);
        }
    }
    u64 bal = __ballot(p);
    __shared__ u32 wb[4]; __shared__ u32 base;
    int lane = threadIdx.x & 63, wv = threadIdx.x >> 6;
    if (lane == 0) wb[wv] = (u32)__popcll(bal);
    __syncthreads();
    if (threadIdx.x == 0) {
        u32 run = 0;
        for (int q = 0; q < 4; ++q) { u32 v = wb[q]; wb[q] = run; run += v; }
        base = run ? atomicAdd(&llen0[bc], run) : 0u;
    }
    __syncthreads();
    if (p) {
        u32 pos = base + wb[wv] + (u32)__popcll(bal & ((1ull << lane) - 1ull));
        if (pos < CAP)
            L0[(size_t)bc * CAP + pos] = ((u64)hi << 32) | (u32)n;
    }
}

// headsort with FUSED per-bc threshold (the single R13 delta vs R10):
// 1) zero next-round hist/llen slice (was k_thresh's job; unconditional, before S check)
// 2) wave 0 computes this bc's bin threshold t (verbatim R10 k_thresh math)
// 3) gather bins<=t (<=GCAP), LDS bitonic sort, emit head arrays  [R10-proven body]
__global__ __launch_bounds__(1024) void k_headsort(const u64* __restrict__ list,
                                                   const u32* __restrict__ llen_cur,
                                                   const u32* __restrict__ hc,
                                                   u32* __restrict__ hn,
                                                   u32* __restrict__ ln,
                                                   const float4* __restrict__ boxes,
                                                   const u32* __restrict__ S_arr,
                                                   u64* __restrict__ headkey,
                                                   float4* __restrict__ headbox,
                                                   float* __restrict__ headarea,
                                                   u32* __restrict__ hl_arr,
                                                   u64* __restrict__ hmax_arr,
                                                   int Nn, int Cc) {
    int bc = blockIdx.x, b = bc / Cc;
    int tid = threadIdx.x, lane = tid & 63, wv = tid >> 6;
    __shared__ u64 buf[4096];   // 32 KB
    __shared__ u32 gcnt;
    __shared__ int s_t;
    // (1) zero next-round state for this bc
    for (int i = tid; i < NBINS; i += 1024) hn[bc * NBINS + i] = 0;
    if (tid == 0) { ln[bc] = 0; gcnt = 0; }
    __syncthreads();
    if ((int)S_arr[bc] >= MAXSEL) { if (tid == 0) hl_arr[bc] = 0; return; }
    int len = (int)llen_cur[bc]; if (len > CAP) len = CAP;
    // (2) fused threshold on wave 0 (verbatim R10 k_thresh math; whole wave active)
    if (wv == 0) {
        if (lane == 0) s_t = -1;
        const u32* h = hc + bc * NBINS;
        int base = lane * 64;
        u32 s = 0;
        for (int i = 0; i < 64; ++i) s += h[base + i];
        u32 p = s;
        for (int d = 1; d < 64; d <<= 1) { u32 o = __shfl_up(p, d); if (lane >= d) p += o; }
        u32 total = __shfl(p, 63);
        u32 K = total < HEAD ? total : HEAD;
        if (K > 0) {
            u64 bal = __ballot(p >= K);
            int tl = (int)__builtin_ctzll(bal);
            if (lane == tl) {
                u32 cum = p - s;
                for (int i = 0; i < 64; ++i) {
                    cum += h[base + i];
                    if (cum >= K) {
                        s_t = (cum <= GCAP) ? (base + i) : (base + i - 1);
                        break;
                    }
                }
            }
        }
    }
    __syncthreads();
    int t = s_t;
    // (3) gather + sort + emit  [verbatim R10]
    if (t >= 0) {
        const u64* src = list + (size_t)bc * CAP;
        for (int i = tid; i < len; i += 1024) {
            u64 key = src[i];
            if ((int)binof((u32)(key >> 32)) <= t) {
                u32 pos = atomicAdd(&gcnt, 1u);
                if (pos < GCAP) buf[pos] = key;
            }
        }
    }
    __syncthreads();
    int g = (int)gcnt; if (g > GCAP) g = GCAP;
    int SN = 1; while (SN < g) SN <<= 1;
    for (int i = g + tid; i < SN; i += 1024) buf[i] = ~0ull;
    __syncthreads();
    for (int k = 2; k <= SN; k <<= 1) {
        for (int j = k >> 1; j > 0; j >>= 1) {
            for (int idx = tid; idx < SN / 2; idx += 1024) {
                int i = ((idx & ~(j - 1)) << 1) | (idx & (j - 1));
                int q = i | j;
                bool up = ((i & k) == 0);
                u64 x = buf[i], y = buf[q];
                if ((x > y) == up) { buf[i] = y; buf[q] = x; }
            }
            __syncthreads();
        }
    }
    int hl = g < HEAD ? g : HEAD;
    if (tid == 0) { hl_arr[bc] = (u32)hl; hmax_arr[bc] = hl > 0 ? buf[hl - 1] : 0ull; }
    for (int i = tid; i < hl; i += 1024) {
        u64 key = buf[i];
        headkey[bc * HEAD + i] = key;
        float4 bx = boxes[(size_t)b * Nn + (u32)key];
        headbox[bc * HEAD + i] = bx;
        headarea[bc * HEAD + i] = areaf(bx);
    }
}

// triangular suppression masks, row-major u64: masks[bc][r][w]   [R10-proven]
__global__ __launch_bounds__(256) void k_premask(const float4* __restrict__ headbox,
                                                 const float* __restrict__ headarea,
                                                 const u32* __restrict__ hl_arr,
                                                 u64* __restrict__ masks) {
    int blk = blockIdx.x, bc = blk >> 4, rb = blk & 15;
    int hl = (int)hl_arr[bc];
    if (hl <= 0) return;
    __shared__ float4 chB[HEAD];
    __shared__ float  chA[HEAD];
    for (int i = threadIdx.x; i < hl; i += 256) {
        chB[i] = headbox[bc * HEAD + i];
        chA[i] = headarea[bc * HEAD + i];
    }
    __syncthreads();
    int r = (rb << 6) + (threadIdx.x & 63);
    int part = threadIdx.x >> 6;               // 0..3
    if (r >= hl) return;
    float4 a = chB[r]; float aA = chA[r];
    u64* row = masks + ((size_t)bc * HEAD + r) * HW;
    for (int w = part * 4; w < part * 4 + 4; ++w) {
        u64 bits = 0;
        int cb = w << 6;
        int j1 = hl - cb; if (j1 > 64) j1 = 64;
        int j0 = (cb > r) ? 0 : (r + 1 - cb);
        for (int j = j0; j < j1; ++j)
            if (iou_gt2(a, aA, chB[cb + j], chA[cb + j])) bits |= (1ull << j);
        row[w] = bits;
    }
}

// Pure-bitmask greedy chain over the head (wave 0).   [R10-proven]
__global__ __launch_bounds__(1024) void k_chain(const u64* __restrict__ headkey,
                                                const u32* __restrict__ hl_arr,
                                                const u64* __restrict__ masks,
                                                const float4* __restrict__ headbox,
                                                const float* __restrict__ headarea,
                                                u32* __restrict__ sel_n,
                                                float* __restrict__ sel_s,
                                                float4* __restrict__ selb_g,
                                                float* __restrict__ sela_g,
                                                u32* __restrict__ S_arr,
                                                u32* __restrict__ Sold) {
    int bc = blockIdx.x;
    int tid = threadIdx.x, lane = tid & 63;
    __shared__ u64 mrow[HEAD * HW];   // 128 KB
    __shared__ u64 kky[HEAD];         // 8 KB
    __shared__ u32 selidx[MAXSEL];
    __shared__ int s_S;
    int S0 = (int)S_arr[bc];
    if (tid == 0) Sold[bc] = (u32)S0;
    int hl = (int)hl_arr[bc];
    if (hl <= 0 || S0 >= MAXSEL) return;   // uniform
    const u64* gm = masks + (size_t)bc * HEAD * HW;
    for (int i = tid; i < hl * HW; i += 1024) mrow[i] = gm[i];
    for (int i = tid; i < hl; i += 1024) kky[i] = headkey[bc * HEAD + i];
    __syncthreads();
    if (tid < 64) {                   // wave 0 walks
        u64 rem = ~0ull;
        if (lane < HW) {
            int lo = lane << 6;
            rem = (hl >= lo + 64) ? 0ull : (hl <= lo ? ~0ull : ~((1ull << (hl - lo)) - 1ull));
        }
        int S = S0;
        while (S < MAXSEL) {
            bool av = (lane < HW) && (rem != ~0ull);
            u64 bal = __ballot(av);
            if (!bal) break;
            int w0 = (int)__builtin_ctzll(bal);
            u64 nz = __shfl((u64)(~rem), w0);
            int kz = (int)__builtin_ctzll(nz);
            int i = (w0 << 6) + kz;
            if (lane == 0) selidx[S] = (u32)i;
            if (lane < HW) rem |= mrow[i * HW + lane];
            if (lane == w0) rem |= (1ull << kz);
            ++S;
        }
        if (lane == 0) { s_S = S; S_arr[bc] = (u32)S; }
    }
    __syncthreads();
    int S = s_S;
    for (int s = S0 + tid; s < S; s += 1024) {
        u32 i = selidx[s];
        u64 k64 = kky[i];
        sel_n[bc * MAXSEL + s] = (u32)k64;
        sel_s[bc * MAXSEL + s] = __uint_as_float(~(u32)(k64 >> 32));
        selb_g[bc * MAXSEL + s] = headbox[bc * HEAD + i];
        sela_g[bc * MAXSEL + s] = headarea[bc * HEAD + i];
    }
}

// survivor rebuild for next round; skips (kills list) when S >= MAXSEL   [R10-proven]
__global__ __launch_bounds__(256) void k_mark(const float4* __restrict__ boxes,
                                              const u64* __restrict__ Lc,
                                              const u32* __restrict__ llen_c,
                                              const float4* __restrict__ selb_g,
                                              const float* __restrict__ sela_g,
                                              const u32* __restrict__ S_arr,
                                              const u32* __restrict__ Sold,
                                              const u64* __restrict__ hmax_arr,
                                              const u32* __restrict__ hl_arr,
                                              u64* __restrict__ Ln,
                                              u32* __restrict__ llen_n,
                                              u32* __restrict__ hist_n,
                                              int Nn, int Cc) {
    int blk = blockIdx.x, bc = blk / NSEG, seg = blk % NSEG;
    int tid = threadIdx.x, lane = tid & 63, wv = tid >> 6;
    int b = bc / Cc;
    int S0 = (int)Sold[bc], S1 = (int)S_arr[bc];
    if (S1 >= MAXSEL) return;                       // complete: next list stays empty
    int len = (int)llen_c[bc]; if (len > CAP) len = CAP;
    if (len <= 0) return;
    int ns = S1 - S0;
    u64 hmax = ((int)hl_arr[bc] > 0) ? hmax_arr[bc] : 0ull;
    __shared__ float4 sb[MAXSEL];
    __shared__ float  sa[MAXSEL];
    for (int s = tid; s < ns; s += 256) {
        sb[s] = selb_g[bc * MAXSEL + S0 + s];
        sa[s] = sela_g[bc * MAXSEL + S0 + s];
    }
    __syncthreads();
    __shared__ u32 wb[4]; __shared__ u32 base;
    int chunk = (len + NSEG - 1) / NSEG;
    int lo = seg * chunk, hi2 = lo + chunk; if (hi2 > len) hi2 = len;
    const u64* src = Lc + (size_t)bc * CAP;
    u64* dst = Ln + (size_t)bc * CAP;
    for (int st = lo; st < hi2; st += 256) {
        int i = st + tid;
        bool alive = i < hi2; u64 key = 0;
        if (alive) {
            key = src[i];
            if (key <= hmax) alive = false;         // consumed in head
            else {
                float4 bx = boxes[(size_t)b * Nn + (u32)key];
                float aA = areaf(bx);
                for (int s = 0; s < ns; ++s)
                    if (iou_gt2(bx, aA, sb[s], sa[s])) { alive = false; break; }
            }
        }
        u64 bal = __ballot(alive);
        if (lane == 0) wb[wv] = (u32)__popcll(bal);
        __syncthreads();
        if (tid == 0) {
            u32 run = 0;
            for (int q = 0; q < 4; ++q) { u32 v = wb[q]; wb[q] = run; run += v; }
            base = run ? atomicAdd(&llen_n[bc], run) : 0u;
        }
        __syncthreads();
        if (alive) {
            u32 pos = base + wb[wv] + (u32)__popcll(bal & ((1ull << lane) - 1ull));
            if (pos < CAP) dst[pos] = key;
            atomicAdd(&hist_n[bc * NBINS + binof((u32)(key >> 32))], 1u);
        }
        __syncthreads();                            // wb reused next iteration
    }
}

// final: per-batch full sort of C*550 entries (== top_k) + output write   [R10-proven]
__global__ __launch_bounds__(1024) void k_final(const u32* __restrict__ selcnt,
                                                const u32* __restrict__ sel_n,
                                                const float* __restrict__ sel_s,
                                                const float4* __restrict__ boxes,
                                                float* __restrict__ out,
                                                int Nn, int Cc, int Bb) {
    int b = blockIdx.x, tid = threadIdx.x;
    const int TOT = MAXSEL * 2;   // 1100
    __shared__ u64 sk[2048];
    u32 c0 = selcnt[b * Cc + 0];
    u32 c1 = selcnt[b * Cc + 1];
    for (int t = tid; t < 2048; t += 1024) {
        u64 key;
        if (t < TOT) {
            int c = t / MAXSEL, k2 = t % MAXSEL;
            u32 cc = (c == 0) ? c0 : c1;
            float sc = (k2 < (int)cc) ? sel_s[(size_t)(b * Cc + c) * MAXSEL + k2] : NEGV;
            u32 u = __float_as_uint(sc);
            u32 ord = (u & 0x80000000u) ? ~u : (u | 0x80000000u);
            key = (((u64)(~ord)) << 32) | (u32)t;
        } else {
            key = ~0ull;
        }
        sk[t] = key;
    }
    __syncthreads();
    for (int k = 2; k <= 2048; k <<= 1) {
        for (int j = k >> 1; j > 0; j >>= 1) {
            int idx = tid;
            int i = ((idx & ~(j - 1)) << 1) | (idx & (j - 1));
            int p = i | j;
            bool up = ((i & k) == 0);
            u64 x = sk[i], y = sk[p];
            if ((x > y) == up) { sk[i] = y; sk[p] = x; }
            __syncthreads();
        }
    }
    int off_scores = Bb * TOT * 4;
    int off_classes = off_scores + Bb * TOT;
    int off_valid = off_classes + Bb * TOT;
    for (int r = tid; r < TOT; r += 1024) {
        u64 key = sk[r];
        u32 flat = (u32)(key & 0xffffffffull);
        u32 hi = (u32)(key >> 32);
        u32 ord = ~hi;
        float sc = (ord & 0x80000000u) ? __uint_as_float(ord & 0x7fffffffu)
                                       : __uint_as_float(~ord);
        bool valid = sc > -5.0e8f;
        int c = (int)(flat / MAXSEL), k2 = (int)(flat % MAXSEL);
        float4 bxv = make_float4(0.f, 0.f, 0.f, 0.f);
        float so = 0.f, co = 0.f;
        if (valid) {
            u32 n = sel_n[(size_t)(b * Cc + c) * MAXSEL + k2];
            bxv = boxes[(size_t)b * Nn + n];
            so = sc;
            co = (float)c;
        }
        ((float4*)out)[b * TOT + r] = bxv;
        out[off_scores + b * TOT + r] = so;
        out[off_classes + b * TOT + r] = co;
    }
    if (tid == 0) out[off_valid + b] = (float)(c0 + c1);
}

extern "C" void kernel_launch(void* const* d_in, const int* in_sizes, int n_in,
                              void* d_out, int out_size, void* d_ws, size_t ws_size,
                              hipStream_t stream) {
    const float* pred = (const float*)d_in[1];
    float* out = (float*)d_out;
    int Bb = out_size / 6601;            // 4
    int Nn = in_sizes[1] / (6 * Bb);     // 49104
    const int Cc = 2;
    if (Bb <= 0 || Nn <= 0) return;
    int NBC = Bb * Cc;                   // 8
    int TIL = (Nn + 255) / 256;          // 192

    char* ws = (char*)d_ws;
    size_t off = 0;
    auto alloc = [&](size_t bytes) { void* p = ws + off; off = (off + bytes + 255) & ~(size_t)255; return p; };
    float4* boxes   = (float4*)alloc((size_t)Bb * Nn * 16);
    u64* L0         = (u64*)alloc((size_t)NBC * CAP * 8);
    u64* L1         = (u64*)alloc((size_t)NBC * CAP * 8);
    u32* hist       = (u32*)alloc(2 * (size_t)NBC * NBINS * 4);
    u32* llen       = (u32*)alloc(2 * NBC * 4);
    u64* headkey    = (u64*)alloc((size_t)NBC * HEAD * 8);
    float4* headbox = (float4*)alloc((size_t)NBC * HEAD * 16);
    float* headarea = (float*)alloc((size_t)NBC * HEAD * 4);
    u32* hl_arr     = (u32*)alloc(NBC * 4);
    u64* hmax_arr   = (u64*)alloc(NBC * 8);
    u32* sel_n      = (u32*)alloc((size_t)NBC * MAXSEL * 4);
    float* sel_s    = (float*)alloc((size_t)NBC * MAXSEL * 4);
    float4* selb_g  = (float4*)alloc((size_t)NBC * MAXSEL * 16);
    float* sela_g   = (float*)alloc((size_t)NBC * MAXSEL * 4);
    u32* S_arr      = (u32*)alloc(NBC * 4);
    u32* Sold       = (u32*)alloc(NBC * 4);
    u64* masks      = (u64*)alloc((size_t)NBC * HEAD * HW * 8);   // 1 MB
    if (off > ws_size) return;

    int BN = Bb * Nn;
    k_decode<<<(BN + 255) / 256, 256, 0, stream>>>(pred, boxes, hist, llen, S_arr, Sold, BN, NBC);
    k_hist<<<NBC * TIL, 256, 0, stream>>>(pred, hist, L0, llen, Nn, Cc, TIL);

    for (int r = 0; r < TROUNDS; ++r) {
        int cur = r & 1, nxt = (r + 1) & 1;
        u64* Lc = cur ? L1 : L0;
        u64* Ln = nxt ? L1 : L0;
        u32* lc = llen + cur * NBC;
        u32* ln = llen + nxt * NBC;
        u32* hc = hist + (size_t)cur * NBC * NBINS;
        u32* hn = hist + (size_t)nxt * NBC * NBINS;
        k_headsort<<<NBC, 1024, 0, stream>>>(Lc, lc, hc, hn, ln, boxes, S_arr,
                                             headkey, headbox, headarea, hl_arr, hmax_arr, Nn, Cc);
        k_premask<<<NBC * 16, 256, 0, stream>>>(headbox, headarea, hl_arr, masks);
        k_chain<<<NBC, 1024, 0, stream>>>(headkey, hl_arr, masks, headbox, headarea,
                                          sel_n, sel_s, selb_g, sela_g, S_arr, Sold);
        if (r + 1 < TROUNDS)
            k_mark<<<NBC * NSEG, 256, 0, stream>>>(boxes, Lc, lc, selb_g, sela_g, S_arr, Sold,
                                                   hmax_arr, hl_arr, Ln, ln, hn, Nn, Cc);
    }
    k_final<<<Bb, 1024, 0, stream>>>(S_arr, sel_n, sel_s, boxes, out, Nn, Cc, Bb);
}